// Round 9
// baseline (365.660 us; speedup 1.0000x reference)
//
#include <hip/hip_runtime.h>
#include <hip/hip_bf16.h>
#include <stdint.h>

// Problem: B=4, S=1024, HID=768, H=12, D=64
#define S_LEN 1024
#define NHEAD 12
#define NQ 3145728LL  // B*H*S*D elements per Q/K/V matrix

// d_out element offsets (fp32), in reference return order:
// context[4,1024,768], attention_scores[4,12,1024,1024], value_scores,
// context_score(scalar), query_scores, key_scores
static constexpr long long OFF_ATT = 3145728LL;
static constexpr long long OFF_VAL = 53477376LL;
static constexpr long long OFF_CSC = 103809024LL;
static constexpr long long OFF_QRY = 103809025LL;  // odd -> dword stores only
static constexpr long long OFF_KEY = 154140673LL;  // odd -> dword stores only

// ws layout (bf16 element offsets)
static constexpr long long WS_VT = 9437184LL;   // after qkv (3*NQ)
static constexpr long long WS_XB = 12582912LL;  // bf16 X [4096][768]
static constexpr long long WS_WB = 15728640LL;  // bf16 W concat [2304][768]

typedef short bf16x8 __attribute__((ext_vector_type(8)));
typedef float f32x4 __attribute__((ext_vector_type(4)));

__device__ __forceinline__ unsigned short f2bf(float f) {
  return __builtin_bit_cast(unsigned short, __float2bfloat16(f));
}
__device__ __forceinline__ uint32_t pk2(float a, float b) {
  return (uint32_t)f2bf(a) | ((uint32_t)f2bf(b) << 16);
}
__device__ __forceinline__ uint4 cvt8(float4 a, float4 b) {
  return make_uint4(pk2(a.x, a.y), pk2(a.z, a.w), pk2(b.x, b.y), pk2(b.z, b.w));
}
// XOR swizzle on 16B chunks within a row; stride must be >=128 bytes.
__device__ __forceinline__ uint32_t swz(uint32_t row, uint32_t col_bytes, uint32_t stride) {
  return row * stride + (col_bytes ^ ((row & 7u) << 4));
}
#define MFMA16(a, b, c) __builtin_amdgcn_mfma_f32_16x16x32_bf16((a), (b), (c), 0, 0, 0)

// ---------------------------------------------------------------------------
// Kernel 0: fp32 -> bf16 pre-convert of X and Wq|Wk|Wv into workspace.
// Grid 2400 x 256; each thread converts 8 elements (2x float4 -> uint4).
// ---------------------------------------------------------------------------
__global__ __launch_bounds__(256) void tobf16_kernel(
    const float* __restrict__ X, const float* __restrict__ Wq,
    const float* __restrict__ Wk, const float* __restrict__ Wv,
    unsigned short* __restrict__ xb)
{
  const int bx = blockIdx.x;
  const float* src;
  unsigned short* dst;
  long long base;
  if (bx < 1536)      { src = X;  dst = xb;                      base = (long long)bx * 2048; }
  else if (bx < 1824) { src = Wq; dst = xb + (WS_WB - WS_XB);    base = (long long)(bx - 1536) * 2048; }
  else if (bx < 2112) { src = Wk; dst = xb + (WS_WB - WS_XB) + 589824;     base = (long long)(bx - 1824) * 2048; }
  else                { src = Wv; dst = xb + (WS_WB - WS_XB) + 2 * 589824; base = (long long)(bx - 2112) * 2048; }
  const long long i = base + (long long)threadIdx.x * 8;
  float4 a = *(const float4*)(src + i);
  float4 b = *(const float4*)(src + i + 4);
  *(uint4*)(dst + i) = cvt8(a, b);
}

// ---------------------------------------------------------------------------
// Kernel 1: Y = Xb @ Wb^T + bias. 128x128 tiles, BK=64, 12 k-iters, 4 waves
// (each 64x64 = 4x4 frags). Writes bf16 Q/K/V [B,H,S,D] and Vt [B,H,D,S].
// Grid (32, 18).
// ---------------------------------------------------------------------------
__global__ __launch_bounds__(256) void qkv_gemm_kernel(
    const unsigned short* __restrict__ Xb, const unsigned short* __restrict__ Wb,
    const float* __restrict__ B0, const float* __restrict__ B1,
    const float* __restrict__ B2,
    unsigned short* __restrict__ qkv, unsigned short* __restrict__ vt)
{
  __shared__ char lds[32768];  // A tile [128][64] bf16 (16KB) + B tile (16KB)
  const int t = threadIdx.x;
  const int lane = t & 63, w = t >> 6;
  const int g = lane >> 4, l15 = lane & 15;
  const int m0 = blockIdx.x * 128;
  const int n0 = blockIdx.y * 128;  // global col in [0,2304); never crosses a 768-mat
  const int wm = w >> 1, wn = w & 1;
  const int srow = t >> 1, sch0 = (t & 1) * 4;

  f32x4 acc[4][4] = {};

  for (int kt = 0; kt < 12; ++kt) {
    __syncthreads();
    #pragma unroll
    for (int j = 0; j < 4; ++j) {
      uint4 a = *(const uint4*)(Xb + (size_t)(m0 + srow) * 768 + kt * 64 + (sch0 + j) * 8);
      *(uint4*)(lds + swz(srow, (sch0 + j) * 16, 128)) = a;
      uint4 b = *(const uint4*)(Wb + (size_t)(n0 + srow) * 768 + kt * 64 + (sch0 + j) * 8);
      *(uint4*)(lds + 16384 + swz(srow, (sch0 + j) * 16, 128)) = b;
    }
    __syncthreads();
    #pragma unroll
    for (int kk = 0; kk < 2; ++kk) {
      bf16x8 af[4], bfr[4];
      #pragma unroll
      for (int mi = 0; mi < 4; ++mi)
        af[mi] = *(const bf16x8*)(lds + swz(wm * 64 + mi * 16 + l15, kk * 64 + g * 16, 128));
      #pragma unroll
      for (int nj = 0; nj < 4; ++nj)
        bfr[nj] = *(const bf16x8*)(lds + 16384 + swz(wn * 64 + nj * 16 + l15, kk * 64 + g * 16, 128));
      #pragma unroll
      for (int mi = 0; mi < 4; ++mi)
        #pragma unroll
        for (int nj = 0; nj < 4; ++nj)
          acc[mi][nj] = MFMA16(af[mi], bfr[nj], acc[mi][nj]);
    }
  }

  #pragma unroll
  for (int mi = 0; mi < 4; ++mi) {
    #pragma unroll
    for (int nj = 0; nj < 4; ++nj) {
      const int ncg = n0 + wn * 64 + nj * 16 + l15;  // [0,2304)
      const int mat = ncg / 768, nc = ncg % 768;
      const int h = nc >> 6, d = nc & 63;
      const float bias = (mat == 0 ? B0 : (mat == 1 ? B1 : B2))[nc];
      const int mbase = m0 + wm * 64 + mi * 16 + g * 4;  // 4 consecutive rows
      const int b = mbase >> 10, s = mbase & 1023;
      unsigned short u[4];
      #pragma unroll
      for (int r = 0; r < 4; ++r) {
        u[r] = f2bf(acc[mi][nj][r] + bias);
        qkv[(size_t)mat * NQ + (((size_t)(b * NHEAD + h)) * S_LEN + (s + r)) * 64 + d] = u[r];
      }
      if (mat == 2) {  // transposed V for the PV step
        *(ushort4*)(vt + (((size_t)(b * NHEAD + h)) * 64 + d) * S_LEN + s) =
            make_ushort4(u[0], u[1], u[2], u[3]);
      }
    }
  }
}

// ---------------------------------------------------------------------------
// Device part A: sym scores G = A A^T / 8 for A in {Q,K,V}.
// 128x128 tile per call; 4 waves of 64x64. (Unchanged from R8 anchor.)
// ---------------------------------------------------------------------------
__device__ __forceinline__ void sym_part(
    char* lds, int sid, const unsigned short* __restrict__ qkv,
    float* __restrict__ out)
{
  const int t = threadIdx.x;
  const int lane = t & 63, w = t >> 6;
  const int g = lane >> 4, l15 = lane & 15;
  const int m0 = (sid & 7) * 128;
  const int n0 = ((sid >> 3) & 7) * 128;
  const int bz = sid >> 6;           // 0..143
  const int typ = bz / 48, bh = bz % 48;
  const unsigned short* A = qkv + (size_t)typ * NQ + (size_t)bh * (S_LEN * 64);
  const int srow = t >> 1, hf = t & 1;
  {
    const uint4* sa = (const uint4*)(A + (size_t)(m0 + srow) * 64 + hf * 32);
    #pragma unroll
    for (int j = 0; j < 4; ++j)
      *(uint4*)(lds + swz(srow, hf * 64 + j * 16, 128)) = sa[j];
    const uint4* sb = (const uint4*)(A + (size_t)(n0 + srow) * 64 + hf * 32);
    #pragma unroll
    for (int j = 0; j < 4; ++j)
      *(uint4*)(lds + 16384 + swz(srow, hf * 64 + j * 16, 128)) = sb[j];
  }
  __syncthreads();
  const int wm = w >> 1, wn = w & 1;
  f32x4 acc[4][4] = {};
  #pragma unroll
  for (int kk = 0; kk < 2; ++kk) {
    bf16x8 af[4], bfr[4];
    #pragma unroll
    for (int mi = 0; mi < 4; ++mi)
      af[mi] = *(const bf16x8*)(lds + swz(wm * 64 + mi * 16 + l15, kk * 64 + g * 16, 128));
    #pragma unroll
    for (int nj = 0; nj < 4; ++nj)
      bfr[nj] = *(const bf16x8*)(lds + 16384 + swz(wn * 64 + nj * 16 + l15, kk * 64 + g * 16, 128));
    #pragma unroll
    for (int mi = 0; mi < 4; ++mi)
      #pragma unroll
      for (int nj = 0; nj < 4; ++nj)
        acc[mi][nj] = MFMA16(af[mi], bfr[nj], acc[mi][nj]);
  }
  if (typ == 2) {
    // Symmetry trick: store frag at the TRANSPOSED location -> float4 stores.
    float* O = out + OFF_VAL + (size_t)bh * (1024ull * 1024);
    #pragma unroll
    for (int mi = 0; mi < 4; ++mi)
      #pragma unroll
      for (int nj = 0; nj < 4; ++nj) {
        f32x4 v = acc[mi][nj] * 0.125f;
        *(f32x4*)(O + (size_t)(n0 + wn * 64 + nj * 16 + l15) * 1024 +
                  (m0 + wm * 64 + mi * 16 + g * 4)) = v;
      }
  } else {
    float* O = out + (typ == 0 ? OFF_QRY : OFF_KEY) + (size_t)bh * (1024ull * 1024);
    #pragma unroll
    for (int mi = 0; mi < 4; ++mi)
      #pragma unroll
      for (int nj = 0; nj < 4; ++nj)
        #pragma unroll
        for (int r = 0; r < 4; ++r)
          O[(size_t)(m0 + wm * 64 + mi * 16 + g * 4 + r) * 1024 +
            (n0 + wn * 64 + nj * 16 + l15)] = acc[mi][nj][r] * 0.125f;
  }
}

// ---------------------------------------------------------------------------
// Device part B: fused attention_scores write + online softmax + context.
// S^T = mfma(K, Q) so each lane owns one q-row. fid in [0,768).
// DELTA vs R8: V fragments read directly from L2-resident vt (no LDS
// staging); P-LDS at 16384; kernel LDS 49152 -> 32768 (3 -> 5 blocks/CU).
// ---------------------------------------------------------------------------
__device__ __forceinline__ void flash_part(
    char* lds, int fid, const unsigned short* __restrict__ qkv,
    const unsigned short* __restrict__ vt, const float* __restrict__ mask,
    float* __restrict__ out)
{
  const int t = threadIdx.x;
  const int lane = t & 63, w = t >> 6;
  const int g = lane >> 4, l15 = lane & 15;
  const int q0 = (fid & 15) * 64;
  const int bh = fid >> 4, b = bh / NHEAD, h = bh % NHEAD;
  const unsigned short* Qp  = qkv + (size_t)bh * (S_LEN * 64);
  const unsigned short* Kp  = qkv + NQ + (size_t)bh * (S_LEN * 64);
  const unsigned short* Vtp = vt + (size_t)bh * (S_LEN * 64);
  const int qrow = q0 + w * 16 + l15;  // this lane's q row

  bf16x8 qf[2];
  qf[0] = *(const bf16x8*)(Qp + (size_t)qrow * 64 + g * 8);
  qf[1] = *(const bf16x8*)(Qp + (size_t)qrow * 64 + 32 + g * 8);

  float m_run = -1e30f, l_run = 0.f;
  f32x4 o[4] = {};
  float* att = out + OFF_ATT + (size_t)bh * (1024ull * 1024) + (size_t)qrow * 1024;
  const float* mrow = mask + b * S_LEN;
  const int sr2 = t >> 1, hf = t & 1;  // K staging: 128 rows x 128B
  char* Plds = lds + 16384 + w * 4096;

  for (int kt = 0; kt < 8; ++kt) {
    __syncthreads();
    {
      const uint4* sk = (const uint4*)(Kp + (size_t)(kt * 128 + sr2) * 64 + hf * 32);
      #pragma unroll
      for (int j = 0; j < 4; ++j)
        *(uint4*)(lds + swz(sr2, hf * 64 + j * 16, 128)) = sk[j];
    }
    __syncthreads();

    // S^T[k][q] = sum_d K[k][d] Q[q][d]
    f32x4 st[8] = {};
    #pragma unroll
    for (int kk = 0; kk < 2; ++kk)
      #pragma unroll
      for (int mi = 0; mi < 8; ++mi) {
        bf16x8 a = *(const bf16x8*)(lds + swz(mi * 16 + l15, kk * 64 + g * 16, 128));
        st[mi] = MFMA16(a, qf[kk], st[mi]);
      }

    // scale + mask + write scores (lane holds 4 consecutive k for its q row)
    float tmax = -1e30f;
    #pragma unroll
    for (int mi = 0; mi < 8; ++mi) {
      f32x4 mk = *(const f32x4*)(mrow + kt * 128 + mi * 16 + g * 4);
      st[mi] = st[mi] * 0.125f + mk;
      *(f32x4*)(att + kt * 128 + mi * 16 + g * 4) = st[mi];
      #pragma unroll
      for (int r = 0; r < 4; ++r) tmax = fmaxf(tmax, st[mi][r]);
    }
    tmax = fmaxf(tmax, __shfl_xor(tmax, 16));
    tmax = fmaxf(tmax, __shfl_xor(tmax, 32));
    const float mnew = fmaxf(m_run, tmax);
    const float corr = __expf(m_run - mnew);
    float tsum = 0.f;
    #pragma unroll
    for (int mi = 0; mi < 8; ++mi)
      #pragma unroll
      for (int r = 0; r < 4; ++r) {
        float p = __expf(st[mi][r] - mnew);
        st[mi][r] = p;
        tsum += p;
      }
    tsum += __shfl_xor(tsum, 16);
    tsum += __shfl_xor(tsum, 32);
    l_run = l_run * corr + tsum;
    m_run = mnew;
    #pragma unroll
    for (int dj = 0; dj < 4; ++dj) o[dj] *= corr;

    // P -> bf16 -> per-wave LDS [16 q rows][128 k], swizzled
    #pragma unroll
    for (int mi = 0; mi < 8; ++mi) {
      uint2 pw = make_uint2(pk2(st[mi][0], st[mi][1]), pk2(st[mi][2], st[mi][3]));
      *(uint2*)(Plds + swz(l15, mi * 32 + g * 8, 256)) = pw;
    }
    // O^T[d][q] += sum_k Vt[d][k] P[q][k]; V frags direct from L2-resident vt
    #pragma unroll
    for (int kk2 = 0; kk2 < 4; ++kk2) {
      bf16x8 pa = *(const bf16x8*)(Plds + swz(l15, kk2 * 64 + g * 16, 256));
      #pragma unroll
      for (int dj = 0; dj < 4; ++dj) {
        const bf16x8 vf = *(const bf16x8*)(Vtp + (size_t)(dj * 16 + l15) * 1024 +
                                           kt * 128 + kk2 * 32 + g * 8);
        o[dj] = MFMA16(vf, pa, o[dj]);
      }
    }
  }

  const float inv = 1.f / l_run;
  #pragma unroll
  for (int dj = 0; dj < 4; ++dj) {
    f32x4 v = o[dj] * inv;
    *(f32x4*)(out + ((size_t)b * S_LEN + qrow) * 768 + h * 64 + dj * 16 + g * 4) = v;
  }
}

// ---------------------------------------------------------------------------
// Kernel 2: merged sym+flash. Grid 9984 = 768*13. Every 13th block is a flash
// block so write-bound sym blocks and compute-phase flash blocks co-reside on
// each CU. 32KB LDS -> 5 blocks/CU (delta under test).
// ---------------------------------------------------------------------------
__global__ __launch_bounds__(256) void fused_scores_attn_kernel(
    const unsigned short* __restrict__ qkv, const unsigned short* __restrict__ vt,
    const float* __restrict__ mask, float* __restrict__ out)
{
  __shared__ char lds[32768];
  const int bid = blockIdx.x;
  if (bid == 9983 && threadIdx.x == 0) out[OFF_CSC] = 0.f;
  if (bid % 13 == 0) {
    flash_part(lds, bid / 13, qkv, vt, mask, out);
  } else {
    sym_part(lds, bid - bid / 13 - 1, qkv, out);
  }
}

extern "C" void kernel_launch(void* const* d_in, const int* in_sizes, int n_in,
                              void* d_out, int out_size, void* d_ws, size_t ws_size,
                              hipStream_t stream) {
  (void)in_sizes; (void)n_in; (void)out_size; (void)ws_size;
  const float* X  = (const float*)d_in[0];
  const float* mk = (const float*)d_in[1];
  const float* Wq = (const float*)d_in[2];
  const float* bq = (const float*)d_in[3];
  const float* Wk = (const float*)d_in[4];
  const float* bk = (const float*)d_in[5];
  const float* Wv = (const float*)d_in[6];
  const float* bv = (const float*)d_in[7];
  float* out = (float*)d_out;
  unsigned short* ws = (unsigned short*)d_ws;
  unsigned short* qkv = ws;            // bf16 Q|K|V [B,H,S,D]
  unsigned short* vt  = ws + WS_VT;    // bf16 Vt [B,H,D,S]
  unsigned short* xb  = ws + WS_XB;    // bf16 X, then W concat at WS_WB

  tobf16_kernel<<<2400, 256, 0, stream>>>(X, Wq, Wk, Wv, xb);
  qkv_gemm_kernel<<<dim3(32, 18), 256, 0, stream>>>(xb, ws + WS_WB, bq, bk, bv, qkv, vt);
  fused_scores_attn_kernel<<<9984, 256, 0, stream>>>(qkv, vt, mk, out);
}

// Round 10
// 280.209 us; speedup vs baseline: 1.3050x; 1.3050x over previous
//
#include <hip/hip_runtime.h>
#include <hip/hip_bf16.h>
#include <stdint.h>

// Problem: B=4, S=1024, HID=768, H=12, D=64
#define S_LEN 1024
#define NHEAD 12
#define NQ 3145728LL  // B*H*S*D elements per Q/K/V matrix

// d_out element offsets (fp32), in reference return order:
// context[4,1024,768], attention_scores[4,12,1024,1024], value_scores,
// context_score(scalar), query_scores, key_scores
static constexpr long long OFF_ATT = 3145728LL;
static constexpr long long OFF_VAL = 53477376LL;
static constexpr long long OFF_CSC = 103809024LL;
static constexpr long long OFF_QRY = 103809025LL;  // odd -> dword stores only
static constexpr long long OFF_KEY = 154140673LL;  // odd -> dword stores only

// ws layout (bf16 element offsets)
static constexpr long long WS_VT = 9437184LL;   // after qkv (3*NQ)
static constexpr long long WS_XB = 12582912LL;  // bf16 X [4096][768]
static constexpr long long WS_WB = 15728640LL;  // bf16 W concat [2304][768]

typedef short bf16x8 __attribute__((ext_vector_type(8)));
typedef float f32x4 __attribute__((ext_vector_type(4)));

__device__ __forceinline__ unsigned short f2bf(float f) {
  return __builtin_bit_cast(unsigned short, __float2bfloat16(f));
}
__device__ __forceinline__ uint32_t pk2(float a, float b) {
  return (uint32_t)f2bf(a) | ((uint32_t)f2bf(b) << 16);
}
__device__ __forceinline__ uint4 cvt8(float4 a, float4 b) {
  return make_uint4(pk2(a.x, a.y), pk2(a.z, a.w), pk2(b.x, b.y), pk2(b.z, b.w));
}
// XOR swizzle on 16B chunks within a row; stride must be >=128 bytes.
__device__ __forceinline__ uint32_t swz(uint32_t row, uint32_t col_bytes, uint32_t stride) {
  return row * stride + (col_bytes ^ ((row & 7u) << 4));
}
#define MFMA16(a, b, c) __builtin_amdgcn_mfma_f32_16x16x32_bf16((a), (b), (c), 0, 0, 0)

// ---------------------------------------------------------------------------
// Kernel 0: fp32 -> bf16 pre-convert of X and Wq|Wk|Wv into workspace.
// Grid 2400 x 256; each thread converts 8 elements (2x float4 -> uint4).
// ---------------------------------------------------------------------------
__global__ __launch_bounds__(256) void tobf16_kernel(
    const float* __restrict__ X, const float* __restrict__ Wq,
    const float* __restrict__ Wk, const float* __restrict__ Wv,
    unsigned short* __restrict__ xb)
{
  const int bx = blockIdx.x;
  const float* src;
  unsigned short* dst;
  long long base;
  if (bx < 1536)      { src = X;  dst = xb;                      base = (long long)bx * 2048; }
  else if (bx < 1824) { src = Wq; dst = xb + (WS_WB - WS_XB);    base = (long long)(bx - 1536) * 2048; }
  else if (bx < 2112) { src = Wk; dst = xb + (WS_WB - WS_XB) + 589824;     base = (long long)(bx - 1824) * 2048; }
  else                { src = Wv; dst = xb + (WS_WB - WS_XB) + 2 * 589824; base = (long long)(bx - 2112) * 2048; }
  const long long i = base + (long long)threadIdx.x * 8;
  float4 a = *(const float4*)(src + i);
  float4 b = *(const float4*)(src + i + 4);
  *(uint4*)(dst + i) = cvt8(a, b);
}

// ---------------------------------------------------------------------------
// Kernel 1: Y = Xb @ Wb^T + bias. 128x128 tiles, BK=64, 12 k-iters, 4 waves
// (each 64x64 = 4x4 frags). Writes bf16 Q/K/V [B,H,S,D] and Vt [B,H,D,S].
// Grid (32, 18).
// ---------------------------------------------------------------------------
__global__ __launch_bounds__(256) void qkv_gemm_kernel(
    const unsigned short* __restrict__ Xb, const unsigned short* __restrict__ Wb,
    const float* __restrict__ B0, const float* __restrict__ B1,
    const float* __restrict__ B2,
    unsigned short* __restrict__ qkv, unsigned short* __restrict__ vt)
{
  __shared__ char lds[32768];  // A tile [128][64] bf16 (16KB) + B tile (16KB)
  const int t = threadIdx.x;
  const int lane = t & 63, w = t >> 6;
  const int g = lane >> 4, l15 = lane & 15;
  const int m0 = blockIdx.x * 128;
  const int n0 = blockIdx.y * 128;  // global col in [0,2304); never crosses a 768-mat
  const int wm = w >> 1, wn = w & 1;
  const int srow = t >> 1, sch0 = (t & 1) * 4;

  f32x4 acc[4][4] = {};

  for (int kt = 0; kt < 12; ++kt) {
    __syncthreads();
    #pragma unroll
    for (int j = 0; j < 4; ++j) {
      uint4 a = *(const uint4*)(Xb + (size_t)(m0 + srow) * 768 + kt * 64 + (sch0 + j) * 8);
      *(uint4*)(lds + swz(srow, (sch0 + j) * 16, 128)) = a;
      uint4 b = *(const uint4*)(Wb + (size_t)(n0 + srow) * 768 + kt * 64 + (sch0 + j) * 8);
      *(uint4*)(lds + 16384 + swz(srow, (sch0 + j) * 16, 128)) = b;
    }
    __syncthreads();
    #pragma unroll
    for (int kk = 0; kk < 2; ++kk) {
      bf16x8 af[4], bfr[4];
      #pragma unroll
      for (int mi = 0; mi < 4; ++mi)
        af[mi] = *(const bf16x8*)(lds + swz(wm * 64 + mi * 16 + l15, kk * 64 + g * 16, 128));
      #pragma unroll
      for (int nj = 0; nj < 4; ++nj)
        bfr[nj] = *(const bf16x8*)(lds + 16384 + swz(wn * 64 + nj * 16 + l15, kk * 64 + g * 16, 128));
      #pragma unroll
      for (int mi = 0; mi < 4; ++mi)
        #pragma unroll
        for (int nj = 0; nj < 4; ++nj)
          acc[mi][nj] = MFMA16(af[mi], bfr[nj], acc[mi][nj]);
    }
  }

  #pragma unroll
  for (int mi = 0; mi < 4; ++mi) {
    #pragma unroll
    for (int nj = 0; nj < 4; ++nj) {
      const int ncg = n0 + wn * 64 + nj * 16 + l15;  // [0,2304)
      const int mat = ncg / 768, nc = ncg % 768;
      const int h = nc >> 6, d = nc & 63;
      const float bias = (mat == 0 ? B0 : (mat == 1 ? B1 : B2))[nc];
      const int mbase = m0 + wm * 64 + mi * 16 + g * 4;  // 4 consecutive rows
      const int b = mbase >> 10, s = mbase & 1023;
      unsigned short u[4];
      #pragma unroll
      for (int r = 0; r < 4; ++r) {
        u[r] = f2bf(acc[mi][nj][r] + bias);
        qkv[(size_t)mat * NQ + (((size_t)(b * NHEAD + h)) * S_LEN + (s + r)) * 64 + d] = u[r];
      }
      if (mat == 2) {  // transposed V for the PV step
        *(ushort4*)(vt + (((size_t)(b * NHEAD + h)) * 64 + d) * S_LEN + s) =
            make_ushort4(u[0], u[1], u[2], u[3]);
      }
    }
  }
}

// ---------------------------------------------------------------------------
// Device part A: sym scores G = A A^T / 8 for A in {Q,K,V}.
// 128x128 tile per call; 4 waves of 64x64. (Unchanged from R8 anchor.)
// ---------------------------------------------------------------------------
__device__ __forceinline__ void sym_part(
    char* lds, int sid, const unsigned short* __restrict__ qkv,
    float* __restrict__ out)
{
  const int t = threadIdx.x;
  const int lane = t & 63, w = t >> 6;
  const int g = lane >> 4, l15 = lane & 15;
  const int m0 = (sid & 7) * 128;
  const int n0 = ((sid >> 3) & 7) * 128;
  const int bz = sid >> 6;           // 0..143
  const int typ = bz / 48, bh = bz % 48;
  const unsigned short* A = qkv + (size_t)typ * NQ + (size_t)bh * (S_LEN * 64);
  const int srow = t >> 1, hf = t & 1;
  {
    const uint4* sa = (const uint4*)(A + (size_t)(m0 + srow) * 64 + hf * 32);
    #pragma unroll
    for (int j = 0; j < 4; ++j)
      *(uint4*)(lds + swz(srow, hf * 64 + j * 16, 128)) = sa[j];
    const uint4* sb = (const uint4*)(A + (size_t)(n0 + srow) * 64 + hf * 32);
    #pragma unroll
    for (int j = 0; j < 4; ++j)
      *(uint4*)(lds + 16384 + swz(srow, hf * 64 + j * 16, 128)) = sb[j];
  }
  __syncthreads();
  const int wm = w >> 1, wn = w & 1;
  f32x4 acc[4][4] = {};
  #pragma unroll
  for (int kk = 0; kk < 2; ++kk) {
    bf16x8 af[4], bfr[4];
    #pragma unroll
    for (int mi = 0; mi < 4; ++mi)
      af[mi] = *(const bf16x8*)(lds + swz(wm * 64 + mi * 16 + l15, kk * 64 + g * 16, 128));
    #pragma unroll
    for (int nj = 0; nj < 4; ++nj)
      bfr[nj] = *(const bf16x8*)(lds + 16384 + swz(wn * 64 + nj * 16 + l15, kk * 64 + g * 16, 128));
    #pragma unroll
    for (int mi = 0; mi < 4; ++mi)
      #pragma unroll
      for (int nj = 0; nj < 4; ++nj)
        acc[mi][nj] = MFMA16(af[mi], bfr[nj], acc[mi][nj]);
  }
  if (typ == 2) {
    // Symmetry trick: store frag at the TRANSPOSED location -> float4 stores.
    float* O = out + OFF_VAL + (size_t)bh * (1024ull * 1024);
    #pragma unroll
    for (int mi = 0; mi < 4; ++mi)
      #pragma unroll
      for (int nj = 0; nj < 4; ++nj) {
        f32x4 v = acc[mi][nj] * 0.125f;
        *(f32x4*)(O + (size_t)(n0 + wn * 64 + nj * 16 + l15) * 1024 +
                  (m0 + wm * 64 + mi * 16 + g * 4)) = v;
      }
  } else {
    float* O = out + (typ == 0 ? OFF_QRY : OFF_KEY) + (size_t)bh * (1024ull * 1024);
    #pragma unroll
    for (int mi = 0; mi < 4; ++mi)
      #pragma unroll
      for (int nj = 0; nj < 4; ++nj)
        #pragma unroll
        for (int r = 0; r < 4; ++r)
          O[(size_t)(m0 + wm * 64 + mi * 16 + g * 4 + r) * 1024 +
            (n0 + wn * 64 + nj * 16 + l15)] = acc[mi][nj][r] * 0.125f;
  }
}

// ---------------------------------------------------------------------------
// Device part B: fused attention_scores write + online softmax + context.
// S^T = mfma(K, Q) so each lane owns one q-row. fid in [0,768).
// (R2/R8 anchor form: K and Vt staged in LDS, 48KB total.)
// ---------------------------------------------------------------------------
__device__ __forceinline__ void flash_part(
    char* lds, int fid, const unsigned short* __restrict__ qkv,
    const unsigned short* __restrict__ vt, const float* __restrict__ mask,
    float* __restrict__ out)
{
  const int t = threadIdx.x;
  const int lane = t & 63, w = t >> 6;
  const int g = lane >> 4, l15 = lane & 15;
  const int q0 = (fid & 15) * 64;
  const int bh = fid >> 4, b = bh / NHEAD, h = bh % NHEAD;
  const unsigned short* Qp  = qkv + (size_t)bh * (S_LEN * 64);
  const unsigned short* Kp  = qkv + NQ + (size_t)bh * (S_LEN * 64);
  const unsigned short* Vtp = vt + (size_t)bh * (S_LEN * 64);
  const int qrow = q0 + w * 16 + l15;  // this lane's q row

  bf16x8 qf[2];
  qf[0] = *(const bf16x8*)(Qp + (size_t)qrow * 64 + g * 8);
  qf[1] = *(const bf16x8*)(Qp + (size_t)qrow * 64 + 32 + g * 8);

  float m_run = -1e30f, l_run = 0.f;
  f32x4 o[4] = {};
  float* att = out + OFF_ATT + (size_t)bh * (1024ull * 1024) + (size_t)qrow * 1024;
  const float* mrow = mask + b * S_LEN;
  const int sr2 = t >> 1, hf = t & 1;  // K staging: 128 rows x 128B
  const int sr4 = t >> 2, qr = t & 3;  // Vt staging: 64 rows x 256B
  char* Plds = lds + 32768 + w * 4096;

  for (int kt = 0; kt < 8; ++kt) {
    __syncthreads();
    {
      const uint4* sk = (const uint4*)(Kp + (size_t)(kt * 128 + sr2) * 64 + hf * 32);
      #pragma unroll
      for (int j = 0; j < 4; ++j)
        *(uint4*)(lds + swz(sr2, hf * 64 + j * 16, 128)) = sk[j];
      const uint4* sv = (const uint4*)(Vtp + (size_t)sr4 * S_LEN + kt * 128 + qr * 32);
      #pragma unroll
      for (int j = 0; j < 4; ++j)
        *(uint4*)(lds + 16384 + swz(sr4, qr * 64 + j * 16, 256)) = sv[j];
    }
    __syncthreads();

    // S^T[k][q] = sum_d K[k][d] Q[q][d]
    f32x4 st[8] = {};
    #pragma unroll
    for (int kk = 0; kk < 2; ++kk)
      #pragma unroll
      for (int mi = 0; mi < 8; ++mi) {
        bf16x8 a = *(const bf16x8*)(lds + swz(mi * 16 + l15, kk * 64 + g * 16, 128));
        st[mi] = MFMA16(a, qf[kk], st[mi]);
      }

    // scale + mask + write scores (lane holds 4 consecutive k for its q row)
    float tmax = -1e30f;
    #pragma unroll
    for (int mi = 0; mi < 8; ++mi) {
      f32x4 mk = *(const f32x4*)(mrow + kt * 128 + mi * 16 + g * 4);
      st[mi] = st[mi] * 0.125f + mk;
      *(f32x4*)(att + kt * 128 + mi * 16 + g * 4) = st[mi];
      #pragma unroll
      for (int r = 0; r < 4; ++r) tmax = fmaxf(tmax, st[mi][r]);
    }
    tmax = fmaxf(tmax, __shfl_xor(tmax, 16));
    tmax = fmaxf(tmax, __shfl_xor(tmax, 32));
    const float mnew = fmaxf(m_run, tmax);
    const float corr = __expf(m_run - mnew);
    float tsum = 0.f;
    #pragma unroll
    for (int mi = 0; mi < 8; ++mi)
      #pragma unroll
      for (int r = 0; r < 4; ++r) {
        float p = __expf(st[mi][r] - mnew);
        st[mi][r] = p;
        tsum += p;
      }
    tsum += __shfl_xor(tsum, 16);
    tsum += __shfl_xor(tsum, 32);
    l_run = l_run * corr + tsum;
    m_run = mnew;
    #pragma unroll
    for (int dj = 0; dj < 4; ++dj) o[dj] *= corr;

    // P -> bf16 -> per-wave LDS [16 q rows][128 k], swizzled
    #pragma unroll
    for (int mi = 0; mi < 8; ++mi) {
      uint2 pw = make_uint2(pk2(st[mi][0], st[mi][1]), pk2(st[mi][2], st[mi][3]));
      *(uint2*)(Plds + swz(l15, mi * 32 + g * 8, 256)) = pw;
    }
    // O^T[d][q] += sum_k Vt[d][k] P[q][k]
    #pragma unroll
    for (int kk2 = 0; kk2 < 4; ++kk2) {
      bf16x8 pa = *(const bf16x8*)(Plds + swz(l15, kk2 * 64 + g * 16, 256));
      #pragma unroll
      for (int dj = 0; dj < 4; ++dj) {
        bf16x8 va = *(const bf16x8*)(lds + 16384 + swz(dj * 16 + l15, kk2 * 64 + g * 16, 256));
        o[dj] = MFMA16(va, pa, o[dj]);
      }
    }
  }

  const float inv = 1.f / l_run;
  #pragma unroll
  for (int dj = 0; dj < 4; ++dj) {
    f32x4 v = o[dj] * inv;
    *(f32x4*)(out + ((size_t)b * S_LEN + qrow) * 768 + h * 64 + dj * 16 + g * 4) = v;
  }
}

// ---------------------------------------------------------------------------
// Kernel 2: merged sym+flash. Grid 9984 = 768*13.
// DELTA vs R8 anchor: XCD-aware bijective swizzle (T1). 9984 = 8 x 1248, so
// logical id = (bid0 & 7) * 1248 + (bid0 >> 3): each XCD owns a contiguous
// logical range -> consecutive sym m-blocks of a score-matrix slab share one
// L2 (write assembly + operand reuse); flash blocks co-locate with their bh.
// ---------------------------------------------------------------------------
__global__ __launch_bounds__(256) void fused_scores_attn_kernel(
    const unsigned short* __restrict__ qkv, const unsigned short* __restrict__ vt,
    const float* __restrict__ mask, float* __restrict__ out)
{
  __shared__ char lds[49152];
  const int bid0 = blockIdx.x;
  const int bid = (bid0 & 7) * 1248 + (bid0 >> 3);  // XCD-chunked logical id
  if (bid == 9983 && threadIdx.x == 0) out[OFF_CSC] = 0.f;
  if (bid % 13 == 0) {
    flash_part(lds, bid / 13, qkv, vt, mask, out);
  } else {
    sym_part(lds, bid - bid / 13 - 1, qkv, out);
  }
}

extern "C" void kernel_launch(void* const* d_in, const int* in_sizes, int n_in,
                              void* d_out, int out_size, void* d_ws, size_t ws_size,
                              hipStream_t stream) {
  (void)in_sizes; (void)n_in; (void)out_size; (void)ws_size;
  const float* X  = (const float*)d_in[0];
  const float* mk = (const float*)d_in[1];
  const float* Wq = (const float*)d_in[2];
  const float* bq = (const float*)d_in[3];
  const float* Wk = (const float*)d_in[4];
  const float* bk = (const float*)d_in[5];
  const float* Wv = (const float*)d_in[6];
  const float* bv = (const float*)d_in[7];
  float* out = (float*)d_out;
  unsigned short* ws = (unsigned short*)d_ws;
  unsigned short* qkv = ws;            // bf16 Q|K|V [B,H,S,D]
  unsigned short* vt  = ws + WS_VT;    // bf16 Vt [B,H,D,S]
  unsigned short* xb  = ws + WS_XB;    // bf16 X, then W concat at WS_WB

  tobf16_kernel<<<2400, 256, 0, stream>>>(X, Wq, Wk, Wv, xb);
  qkv_gemm_kernel<<<dim3(32, 18), 256, 0, stream>>>(xb, ws + WS_WB, bq, bk, bv, qkv, vt);
  fused_scores_attn_kernel<<<9984, 256, 0, stream>>>(qkv, vt, mk, out);
}

// Round 11
// 266.886 us; speedup vs baseline: 1.3701x; 1.0499x over previous
//
#include <hip/hip_runtime.h>
#include <hip/hip_bf16.h>
#include <stdint.h>

// Problem: B=4, S=1024, HID=768, H=12, D=64
#define S_LEN 1024
#define NHEAD 12
#define NQ 3145728LL  // B*H*S*D elements per Q/K/V matrix

// d_out element offsets (fp32), in reference return order:
// context[4,1024,768], attention_scores[4,12,1024,1024], value_scores,
// context_score(scalar), query_scores, key_scores
static constexpr long long OFF_ATT = 3145728LL;
static constexpr long long OFF_VAL = 53477376LL;
static constexpr long long OFF_CSC = 103809024LL;
static constexpr long long OFF_QRY = 103809025LL;  // odd base -> 4B-aligned stores
static constexpr long long OFF_KEY = 154140673LL;  // odd base -> 4B-aligned stores

// ws layout (bf16 element offsets)
static constexpr long long WS_VT = 9437184LL;   // after qkv (3*NQ)
static constexpr long long WS_XB = 12582912LL;  // bf16 X [4096][768]
static constexpr long long WS_WB = 15728640LL;  // bf16 W concat [2304][768]

typedef short bf16x8 __attribute__((ext_vector_type(8)));
typedef float f32x4 __attribute__((ext_vector_type(4)));
// 4-byte-aligned float4: compiler emits dword-aligned global_store_dwordx4
// (gfx950 global stores require only dword alignment).
typedef float f32x4_a4 __attribute__((ext_vector_type(4), aligned(4)));

__device__ __forceinline__ unsigned short f2bf(float f) {
  return __builtin_bit_cast(unsigned short, __float2bfloat16(f));
}
__device__ __forceinline__ uint32_t pk2(float a, float b) {
  return (uint32_t)f2bf(a) | ((uint32_t)f2bf(b) << 16);
}
__device__ __forceinline__ uint4 cvt8(float4 a, float4 b) {
  return make_uint4(pk2(a.x, a.y), pk2(a.z, a.w), pk2(b.x, b.y), pk2(b.z, b.w));
}
// XOR swizzle on 16B chunks within a row; stride must be >=128 bytes.
__device__ __forceinline__ uint32_t swz(uint32_t row, uint32_t col_bytes, uint32_t stride) {
  return row * stride + (col_bytes ^ ((row & 7u) << 4));
}
#define MFMA16(a, b, c) __builtin_amdgcn_mfma_f32_16x16x32_bf16((a), (b), (c), 0, 0, 0)

// ---------------------------------------------------------------------------
// Kernel 0: fp32 -> bf16 pre-convert of X and Wq|Wk|Wv into workspace.
// Grid 2400 x 256; each thread converts 8 elements (2x float4 -> uint4).
// ---------------------------------------------------------------------------
__global__ __launch_bounds__(256) void tobf16_kernel(
    const float* __restrict__ X, const float* __restrict__ Wq,
    const float* __restrict__ Wk, const float* __restrict__ Wv,
    unsigned short* __restrict__ xb)
{
  const int bx = blockIdx.x;
  const float* src;
  unsigned short* dst;
  long long base;
  if (bx < 1536)      { src = X;  dst = xb;                      base = (long long)bx * 2048; }
  else if (bx < 1824) { src = Wq; dst = xb + (WS_WB - WS_XB);    base = (long long)(bx - 1536) * 2048; }
  else if (bx < 2112) { src = Wk; dst = xb + (WS_WB - WS_XB) + 589824;     base = (long long)(bx - 1824) * 2048; }
  else                { src = Wv; dst = xb + (WS_WB - WS_XB) + 2 * 589824; base = (long long)(bx - 2112) * 2048; }
  const long long i = base + (long long)threadIdx.x * 8;
  float4 a = *(const float4*)(src + i);
  float4 b = *(const float4*)(src + i + 4);
  *(uint4*)(dst + i) = cvt8(a, b);
}

// ---------------------------------------------------------------------------
// Kernel 1: Y = Xb @ Wb^T + bias. 128x128 tiles, BK=64, 12 k-iters, 4 waves
// (each 64x64 = 4x4 frags). Writes bf16 Q/K/V [B,H,S,D] and Vt [B,H,D,S].
// Grid (32, 18).
// ---------------------------------------------------------------------------
__global__ __launch_bounds__(256) void qkv_gemm_kernel(
    const unsigned short* __restrict__ Xb, const unsigned short* __restrict__ Wb,
    const float* __restrict__ B0, const float* __restrict__ B1,
    const float* __restrict__ B2,
    unsigned short* __restrict__ qkv, unsigned short* __restrict__ vt)
{
  __shared__ char lds[32768];  // A tile [128][64] bf16 (16KB) + B tile (16KB)
  const int t = threadIdx.x;
  const int lane = t & 63, w = t >> 6;
  const int g = lane >> 4, l15 = lane & 15;
  const int m0 = blockIdx.x * 128;
  const int n0 = blockIdx.y * 128;  // global col in [0,2304); never crosses a 768-mat
  const int wm = w >> 1, wn = w & 1;
  const int srow = t >> 1, sch0 = (t & 1) * 4;

  f32x4 acc[4][4] = {};

  for (int kt = 0; kt < 12; ++kt) {
    __syncthreads();
    #pragma unroll
    for (int j = 0; j < 4; ++j) {
      uint4 a = *(const uint4*)(Xb + (size_t)(m0 + srow) * 768 + kt * 64 + (sch0 + j) * 8);
      *(uint4*)(lds + swz(srow, (sch0 + j) * 16, 128)) = a;
      uint4 b = *(const uint4*)(Wb + (size_t)(n0 + srow) * 768 + kt * 64 + (sch0 + j) * 8);
      *(uint4*)(lds + 16384 + swz(srow, (sch0 + j) * 16, 128)) = b;
    }
    __syncthreads();
    #pragma unroll
    for (int kk = 0; kk < 2; ++kk) {
      bf16x8 af[4], bfr[4];
      #pragma unroll
      for (int mi = 0; mi < 4; ++mi)
        af[mi] = *(const bf16x8*)(lds + swz(wm * 64 + mi * 16 + l15, kk * 64 + g * 16, 128));
      #pragma unroll
      for (int nj = 0; nj < 4; ++nj)
        bfr[nj] = *(const bf16x8*)(lds + 16384 + swz(wn * 64 + nj * 16 + l15, kk * 64 + g * 16, 128));
      #pragma unroll
      for (int mi = 0; mi < 4; ++mi)
        #pragma unroll
        for (int nj = 0; nj < 4; ++nj)
          acc[mi][nj] = MFMA16(af[mi], bfr[nj], acc[mi][nj]);
    }
  }

  #pragma unroll
  for (int mi = 0; mi < 4; ++mi) {
    #pragma unroll
    for (int nj = 0; nj < 4; ++nj) {
      const int ncg = n0 + wn * 64 + nj * 16 + l15;  // [0,2304)
      const int mat = ncg / 768, nc = ncg % 768;
      const int h = nc >> 6, d = nc & 63;
      const float bias = (mat == 0 ? B0 : (mat == 1 ? B1 : B2))[nc];
      const int mbase = m0 + wm * 64 + mi * 16 + g * 4;  // 4 consecutive rows
      const int b = mbase >> 10, s = mbase & 1023;
      unsigned short u[4];
      #pragma unroll
      for (int r = 0; r < 4; ++r) {
        u[r] = f2bf(acc[mi][nj][r] + bias);
        qkv[(size_t)mat * NQ + (((size_t)(b * NHEAD + h)) * S_LEN + (s + r)) * 64 + d] = u[r];
      }
      if (mat == 2) {  // transposed V for the PV step
        *(ushort4*)(vt + (((size_t)(b * NHEAD + h)) * 64 + d) * S_LEN + s) =
            make_ushort4(u[0], u[1], u[2], u[3]);
      }
    }
  }
}

// ---------------------------------------------------------------------------
// Device part A: sym scores G = A A^T / 8 for A in {Q,K,V}.
// 128x128 tile per call; 4 waves of 64x64.
// DELTA vs R10: qry/key now also use the symmetric-transpose store
// (bitwise-exact by MFMA operand commutativity) with 4B-aligned f32x4
// vector stores (global_store_dwordx4 needs only dword alignment), nj-outer
// ordering. 256 scalar-dword store insts/block -> 64 dwordx4 insts.
// ---------------------------------------------------------------------------
__device__ __forceinline__ void sym_part(
    char* lds, int sid, const unsigned short* __restrict__ qkv,
    float* __restrict__ out)
{
  const int t = threadIdx.x;
  const int lane = t & 63, w = t >> 6;
  const int g = lane >> 4, l15 = lane & 15;
  const int m0 = (sid & 7) * 128;
  const int n0 = ((sid >> 3) & 7) * 128;
  const int bz = sid >> 6;           // 0..143
  const int typ = bz / 48, bh = bz % 48;
  const unsigned short* A = qkv + (size_t)typ * NQ + (size_t)bh * (S_LEN * 64);
  const int srow = t >> 1, hf = t & 1;
  {
    const uint4* sa = (const uint4*)(A + (size_t)(m0 + srow) * 64 + hf * 32);
    #pragma unroll
    for (int j = 0; j < 4; ++j)
      *(uint4*)(lds + swz(srow, hf * 64 + j * 16, 128)) = sa[j];
    const uint4* sb = (const uint4*)(A + (size_t)(n0 + srow) * 64 + hf * 32);
    #pragma unroll
    for (int j = 0; j < 4; ++j)
      *(uint4*)(lds + 16384 + swz(srow, hf * 64 + j * 16, 128)) = sb[j];
  }
  __syncthreads();
  const int wm = w >> 1, wn = w & 1;
  f32x4 acc[4][4] = {};
  #pragma unroll
  for (int kk = 0; kk < 2; ++kk) {
    bf16x8 af[4], bfr[4];
    #pragma unroll
    for (int mi = 0; mi < 4; ++mi)
      af[mi] = *(const bf16x8*)(lds + swz(wm * 64 + mi * 16 + l15, kk * 64 + g * 16, 128));
    #pragma unroll
    for (int nj = 0; nj < 4; ++nj)
      bfr[nj] = *(const bf16x8*)(lds + 16384 + swz(wn * 64 + nj * 16 + l15, kk * 64 + g * 16, 128));
    #pragma unroll
    for (int mi = 0; mi < 4; ++mi)
      #pragma unroll
      for (int nj = 0; nj < 4; ++nj)
        acc[mi][nj] = MFMA16(af[mi], bfr[nj], acc[mi][nj]);
  }
  if (typ == 2) {
    // Symmetry trick: store frag at the TRANSPOSED location -> float4 stores.
    float* O = out + OFF_VAL + (size_t)bh * (1024ull * 1024);
    #pragma unroll
    for (int nj = 0; nj < 4; ++nj)
      #pragma unroll
      for (int mi = 0; mi < 4; ++mi) {
        f32x4 v = acc[mi][nj] * 0.125f;
        *(f32x4*)(O + (size_t)(n0 + wn * 64 + nj * 16 + l15) * 1024 +
                  (m0 + wm * 64 + mi * 16 + g * 4)) = v;
      }
  } else {
    // Same transposed layout, 4B-aligned vector stores (odd output base).
    float* O = out + (typ == 0 ? OFF_QRY : OFF_KEY) + (size_t)bh * (1024ull * 1024);
    #pragma unroll
    for (int nj = 0; nj < 4; ++nj)
      #pragma unroll
      for (int mi = 0; mi < 4; ++mi) {
        f32x4 v = acc[mi][nj] * 0.125f;
        *(f32x4_a4*)(O + (size_t)(n0 + wn * 64 + nj * 16 + l15) * 1024 +
                     (m0 + wm * 64 + mi * 16 + g * 4)) = v;
      }
  }
}

// ---------------------------------------------------------------------------
// Device part B: fused attention_scores write + online softmax + context.
// S^T = mfma(K, Q) so each lane owns one q-row. fid in [0,768).
// (R2/R8/R10 anchor form: K and Vt staged in LDS, 48KB total.)
// ---------------------------------------------------------------------------
__device__ __forceinline__ void flash_part(
    char* lds, int fid, const unsigned short* __restrict__ qkv,
    const unsigned short* __restrict__ vt, const float* __restrict__ mask,
    float* __restrict__ out)
{
  const int t = threadIdx.x;
  const int lane = t & 63, w = t >> 6;
  const int g = lane >> 4, l15 = lane & 15;
  const int q0 = (fid & 15) * 64;
  const int bh = fid >> 4, b = bh / NHEAD, h = bh % NHEAD;
  const unsigned short* Qp  = qkv + (size_t)bh * (S_LEN * 64);
  const unsigned short* Kp  = qkv + NQ + (size_t)bh * (S_LEN * 64);
  const unsigned short* Vtp = vt + (size_t)bh * (S_LEN * 64);
  const int qrow = q0 + w * 16 + l15;  // this lane's q row

  bf16x8 qf[2];
  qf[0] = *(const bf16x8*)(Qp + (size_t)qrow * 64 + g * 8);
  qf[1] = *(const bf16x8*)(Qp + (size_t)qrow * 64 + 32 + g * 8);

  float m_run = -1e30f, l_run = 0.f;
  f32x4 o[4] = {};
  float* att = out + OFF_ATT + (size_t)bh * (1024ull * 1024) + (size_t)qrow * 1024;
  const float* mrow = mask + b * S_LEN;
  const int sr2 = t >> 1, hf = t & 1;  // K staging: 128 rows x 128B
  const int sr4 = t >> 2, qr = t & 3;  // Vt staging: 64 rows x 256B
  char* Plds = lds + 32768 + w * 4096;

  for (int kt = 0; kt < 8; ++kt) {
    __syncthreads();
    {
      const uint4* sk = (const uint4*)(Kp + (size_t)(kt * 128 + sr2) * 64 + hf * 32);
      #pragma unroll
      for (int j = 0; j < 4; ++j)
        *(uint4*)(lds + swz(sr2, hf * 64 + j * 16, 128)) = sk[j];
      const uint4* sv = (const uint4*)(Vtp + (size_t)sr4 * S_LEN + kt * 128 + qr * 32);
      #pragma unroll
      for (int j = 0; j < 4; ++j)
        *(uint4*)(lds + 16384 + swz(sr4, qr * 64 + j * 16, 256)) = sv[j];
    }
    __syncthreads();

    // S^T[k][q] = sum_d K[k][d] Q[q][d]
    f32x4 st[8] = {};
    #pragma unroll
    for (int kk = 0; kk < 2; ++kk)
      #pragma unroll
      for (int mi = 0; mi < 8; ++mi) {
        bf16x8 a = *(const bf16x8*)(lds + swz(mi * 16 + l15, kk * 64 + g * 16, 128));
        st[mi] = MFMA16(a, qf[kk], st[mi]);
      }

    // scale + mask + write scores (lane holds 4 consecutive k for its q row)
    float tmax = -1e30f;
    #pragma unroll
    for (int mi = 0; mi < 8; ++mi) {
      f32x4 mk = *(const f32x4*)(mrow + kt * 128 + mi * 16 + g * 4);
      st[mi] = st[mi] * 0.125f + mk;
      *(f32x4*)(att + kt * 128 + mi * 16 + g * 4) = st[mi];
      #pragma unroll
      for (int r = 0; r < 4; ++r) tmax = fmaxf(tmax, st[mi][r]);
    }
    tmax = fmaxf(tmax, __shfl_xor(tmax, 16));
    tmax = fmaxf(tmax, __shfl_xor(tmax, 32));
    const float mnew = fmaxf(m_run, tmax);
    const float corr = __expf(m_run - mnew);
    float tsum = 0.f;
    #pragma unroll
    for (int mi = 0; mi < 8; ++mi)
      #pragma unroll
      for (int r = 0; r < 4; ++r) {
        float p = __expf(st[mi][r] - mnew);
        st[mi][r] = p;
        tsum += p;
      }
    tsum += __shfl_xor(tsum, 16);
    tsum += __shfl_xor(tsum, 32);
    l_run = l_run * corr + tsum;
    m_run = mnew;
    #pragma unroll
    for (int dj = 0; dj < 4; ++dj) o[dj] *= corr;

    // P -> bf16 -> per-wave LDS [16 q rows][128 k], swizzled
    #pragma unroll
    for (int mi = 0; mi < 8; ++mi) {
      uint2 pw = make_uint2(pk2(st[mi][0], st[mi][1]), pk2(st[mi][2], st[mi][3]));
      *(uint2*)(Plds + swz(l15, mi * 32 + g * 8, 256)) = pw;
    }
    // O^T[d][q] += sum_k Vt[d][k] P[q][k]
    #pragma unroll
    for (int kk2 = 0; kk2 < 4; ++kk2) {
      bf16x8 pa = *(const bf16x8*)(Plds + swz(l15, kk2 * 64 + g * 16, 256));
      #pragma unroll
      for (int dj = 0; dj < 4; ++dj) {
        bf16x8 va = *(const bf16x8*)(lds + 16384 + swz(dj * 16 + l15, kk2 * 64 + g * 16, 256));
        o[dj] = MFMA16(va, pa, o[dj]);
      }
    }
  }

  const float inv = 1.f / l_run;
  #pragma unroll
  for (int dj = 0; dj < 4; ++dj) {
    f32x4 v = o[dj] * inv;
    *(f32x4*)(out + ((size_t)b * S_LEN + qrow) * 768 + h * 64 + dj * 16 + g * 4) = v;
  }
}

// ---------------------------------------------------------------------------
// Kernel 2: merged sym+flash. Grid 9984 = 768*13, XCD-aware bijective swizzle
// (9984 = 8 x 1248): each XCD owns a contiguous logical range.
// ---------------------------------------------------------------------------
__global__ __launch_bounds__(256) void fused_scores_attn_kernel(
    const unsigned short* __restrict__ qkv, const unsigned short* __restrict__ vt,
    const float* __restrict__ mask, float* __restrict__ out)
{
  __shared__ char lds[49152];
  const int bid0 = blockIdx.x;
  const int bid = (bid0 & 7) * 1248 + (bid0 >> 3);  // XCD-chunked logical id
  if (bid == 9983 && threadIdx.x == 0) out[OFF_CSC] = 0.f;
  if (bid % 13 == 0) {
    flash_part(lds, bid / 13, qkv, vt, mask, out);
  } else {
    sym_part(lds, bid - bid / 13 - 1, qkv, out);
  }
}

extern "C" void kernel_launch(void* const* d_in, const int* in_sizes, int n_in,
                              void* d_out, int out_size, void* d_ws, size_t ws_size,
                              hipStream_t stream) {
  (void)in_sizes; (void)n_in; (void)out_size; (void)ws_size;
  const float* X  = (const float*)d_in[0];
  const float* mk = (const float*)d_in[1];
  const float* Wq = (const float*)d_in[2];
  const float* bq = (const float*)d_in[3];
  const float* Wk = (const float*)d_in[4];
  const float* bk = (const float*)d_in[5];
  const float* Wv = (const float*)d_in[6];
  const float* bv = (const float*)d_in[7];
  float* out = (float*)d_out;
  unsigned short* ws = (unsigned short*)d_ws;
  unsigned short* qkv = ws;            // bf16 Q|K|V [B,H,S,D]
  unsigned short* vt  = ws + WS_VT;    // bf16 Vt [B,H,D,S]
  unsigned short* xb  = ws + WS_XB;    // bf16 X, then W concat at WS_WB

  tobf16_kernel<<<2400, 256, 0, stream>>>(X, Wq, Wk, Wv, xb);
  qkv_gemm_kernel<<<dim3(32, 18), 256, 0, stream>>>(xb, ws + WS_WB, bq, bk, bv, qkv, vt);
  fused_scores_attn_kernel<<<9984, 256, 0, stream>>>(qkv, vt, mk, out);
}

// Round 12
// 237.744 us; speedup vs baseline: 1.5380x; 1.1226x over previous
//
#include <hip/hip_runtime.h>
#include <hip/hip_bf16.h>
#include <stdint.h>

// Problem: B=4, S=1024, HID=768, H=12, D=64
#define S_LEN 1024
#define NHEAD 12
#define NQ 3145728LL  // B*H*S*D elements per Q/K/V matrix

// d_out element offsets (fp32), in reference return order:
// context[4,1024,768], attention_scores[4,12,1024,1024], value_scores,
// context_score(scalar), query_scores, key_scores
static constexpr long long OFF_ATT = 3145728LL;
static constexpr long long OFF_VAL = 53477376LL;
static constexpr long long OFF_CSC = 103809024LL;
static constexpr long long OFF_QRY = 103809025LL;  // odd base -> 4B-aligned stores
static constexpr long long OFF_KEY = 154140673LL;  // odd base -> 4B-aligned stores

// ws layout (bf16 element offsets)
static constexpr long long WS_VT = 9437184LL;   // after qkv (3*NQ)
static constexpr long long WS_XB = 12582912LL;  // bf16 X [4096][768]
static constexpr long long WS_WB = 15728640LL;  // bf16 W concat [2304][768]

typedef short bf16x8 __attribute__((ext_vector_type(8)));
typedef float f32x4 __attribute__((ext_vector_type(4)));
// 4-byte-aligned float4: compiler emits dword-aligned global_store_dwordx4
// (gfx950 global stores require only dword alignment).
typedef float f32x4_a4 __attribute__((ext_vector_type(4), aligned(4)));

__device__ __forceinline__ unsigned short f2bf(float f) {
  return __builtin_bit_cast(unsigned short, __float2bfloat16(f));
}
__device__ __forceinline__ uint32_t pk2(float a, float b) {
  return (uint32_t)f2bf(a) | ((uint32_t)f2bf(b) << 16);
}
__device__ __forceinline__ uint4 cvt8(float4 a, float4 b) {
  return make_uint4(pk2(a.x, a.y), pk2(a.z, a.w), pk2(b.x, b.y), pk2(b.z, b.w));
}
// XOR swizzle on 16B chunks within a row; stride must be >=128 bytes.
__device__ __forceinline__ uint32_t swz(uint32_t row, uint32_t col_bytes, uint32_t stride) {
  return row * stride + (col_bytes ^ ((row & 7u) << 4));
}
#define MFMA16(a, b, c) __builtin_amdgcn_mfma_f32_16x16x32_bf16((a), (b), (c), 0, 0, 0)

// ---------------------------------------------------------------------------
// Kernel 0: fp32 -> bf16 pre-convert of X and Wq|Wk|Wv into workspace.
// Grid 2400 x 256; each thread converts 8 elements (2x float4 -> uint4).
// ---------------------------------------------------------------------------
__global__ __launch_bounds__(256) void tobf16_kernel(
    const float* __restrict__ X, const float* __restrict__ Wq,
    const float* __restrict__ Wk, const float* __restrict__ Wv,
    unsigned short* __restrict__ xb)
{
  const int bx = blockIdx.x;
  const float* src;
  unsigned short* dst;
  long long base;
  if (bx < 1536)      { src = X;  dst = xb;                      base = (long long)bx * 2048; }
  else if (bx < 1824) { src = Wq; dst = xb + (WS_WB - WS_XB);    base = (long long)(bx - 1536) * 2048; }
  else if (bx < 2112) { src = Wk; dst = xb + (WS_WB - WS_XB) + 589824;     base = (long long)(bx - 1824) * 2048; }
  else                { src = Wv; dst = xb + (WS_WB - WS_XB) + 2 * 589824; base = (long long)(bx - 2112) * 2048; }
  const long long i = base + (long long)threadIdx.x * 8;
  float4 a = *(const float4*)(src + i);
  float4 b = *(const float4*)(src + i + 4);
  *(uint4*)(dst + i) = cvt8(a, b);
}

// ---------------------------------------------------------------------------
// Kernel 1: Y = Xb @ Wb^T + bias. 128x128 tiles, BK=64, 12 k-iters, 4 waves
// (each 64x64 = 4x4 frags). Writes bf16 Q/K/V [B,H,S,D] and Vt [B,H,D,S].
// Grid (32, 18).
// ---------------------------------------------------------------------------
__global__ __launch_bounds__(256) void qkv_gemm_kernel(
    const unsigned short* __restrict__ Xb, const unsigned short* __restrict__ Wb,
    const float* __restrict__ B0, const float* __restrict__ B1,
    const float* __restrict__ B2,
    unsigned short* __restrict__ qkv, unsigned short* __restrict__ vt)
{
  __shared__ char lds[32768];  // A tile [128][64] bf16 (16KB) + B tile (16KB)
  const int t = threadIdx.x;
  const int lane = t & 63, w = t >> 6;
  const int g = lane >> 4, l15 = lane & 15;
  const int m0 = blockIdx.x * 128;
  const int n0 = blockIdx.y * 128;  // global col in [0,2304); never crosses a 768-mat
  const int wm = w >> 1, wn = w & 1;
  const int srow = t >> 1, sch0 = (t & 1) * 4;

  f32x4 acc[4][4] = {};

  for (int kt = 0; kt < 12; ++kt) {
    __syncthreads();
    #pragma unroll
    for (int j = 0; j < 4; ++j) {
      uint4 a = *(const uint4*)(Xb + (size_t)(m0 + srow) * 768 + kt * 64 + (sch0 + j) * 8);
      *(uint4*)(lds + swz(srow, (sch0 + j) * 16, 128)) = a;
      uint4 b = *(const uint4*)(Wb + (size_t)(n0 + srow) * 768 + kt * 64 + (sch0 + j) * 8);
      *(uint4*)(lds + 16384 + swz(srow, (sch0 + j) * 16, 128)) = b;
    }
    __syncthreads();
    #pragma unroll
    for (int kk = 0; kk < 2; ++kk) {
      bf16x8 af[4], bfr[4];
      #pragma unroll
      for (int mi = 0; mi < 4; ++mi)
        af[mi] = *(const bf16x8*)(lds + swz(wm * 64 + mi * 16 + l15, kk * 64 + g * 16, 128));
      #pragma unroll
      for (int nj = 0; nj < 4; ++nj)
        bfr[nj] = *(const bf16x8*)(lds + 16384 + swz(wn * 64 + nj * 16 + l15, kk * 64 + g * 16, 128));
      #pragma unroll
      for (int mi = 0; mi < 4; ++mi)
        #pragma unroll
        for (int nj = 0; nj < 4; ++nj)
          acc[mi][nj] = MFMA16(af[mi], bfr[nj], acc[mi][nj]);
    }
  }

  #pragma unroll
  for (int mi = 0; mi < 4; ++mi) {
    #pragma unroll
    for (int nj = 0; nj < 4; ++nj) {
      const int ncg = n0 + wn * 64 + nj * 16 + l15;  // [0,2304)
      const int mat = ncg / 768, nc = ncg % 768;
      const int h = nc >> 6, d = nc & 63;
      const float bias = (mat == 0 ? B0 : (mat == 1 ? B1 : B2))[nc];
      const int mbase = m0 + wm * 64 + mi * 16 + g * 4;  // 4 consecutive rows
      const int b = mbase >> 10, s = mbase & 1023;
      unsigned short u[4];
      #pragma unroll
      for (int r = 0; r < 4; ++r) {
        u[r] = f2bf(acc[mi][nj][r] + bias);
        qkv[(size_t)mat * NQ + (((size_t)(b * NHEAD + h)) * S_LEN + (s + r)) * 64 + d] = u[r];
      }
      if (mat == 2) {  // transposed V for the PV step
        *(ushort4*)(vt + (((size_t)(b * NHEAD + h)) * 64 + d) * S_LEN + s) =
            make_ushort4(u[0], u[1], u[2], u[3]);
      }
    }
  }
}

// ---------------------------------------------------------------------------
// Device part A: sym scores G = A A^T / 8 for A in {Q,K,V}.
// 128x128 tile per call; 4 waves of 64x64. Symmetric-transpose stores for
// all three outputs (value aligned f32x4; qry/key 4B-aligned f32x4).
// ---------------------------------------------------------------------------
__device__ __forceinline__ void sym_part(
    char* lds, int sid, const unsigned short* __restrict__ qkv,
    float* __restrict__ out)
{
  const int t = threadIdx.x;
  const int lane = t & 63, w = t >> 6;
  const int g = lane >> 4, l15 = lane & 15;
  const int m0 = (sid & 7) * 128;
  const int n0 = ((sid >> 3) & 7) * 128;
  const int bz = sid >> 6;           // 0..143
  const int typ = bz / 48, bh = bz % 48;
  const unsigned short* A = qkv + (size_t)typ * NQ + (size_t)bh * (S_LEN * 64);
  const int srow = t >> 1, hf = t & 1;
  {
    const uint4* sa = (const uint4*)(A + (size_t)(m0 + srow) * 64 + hf * 32);
    #pragma unroll
    for (int j = 0; j < 4; ++j)
      *(uint4*)(lds + swz(srow, hf * 64 + j * 16, 128)) = sa[j];
    const uint4* sb = (const uint4*)(A + (size_t)(n0 + srow) * 64 + hf * 32);
    #pragma unroll
    for (int j = 0; j < 4; ++j)
      *(uint4*)(lds + 16384 + swz(srow, hf * 64 + j * 16, 128)) = sb[j];
  }
  __syncthreads();
  const int wm = w >> 1, wn = w & 1;
  f32x4 acc[4][4] = {};
  #pragma unroll
  for (int kk = 0; kk < 2; ++kk) {
    bf16x8 af[4], bfr[4];
    #pragma unroll
    for (int mi = 0; mi < 4; ++mi)
      af[mi] = *(const bf16x8*)(lds + swz(wm * 64 + mi * 16 + l15, kk * 64 + g * 16, 128));
    #pragma unroll
    for (int nj = 0; nj < 4; ++nj)
      bfr[nj] = *(const bf16x8*)(lds + 16384 + swz(wn * 64 + nj * 16 + l15, kk * 64 + g * 16, 128));
    #pragma unroll
    for (int mi = 0; mi < 4; ++mi)
      #pragma unroll
      for (int nj = 0; nj < 4; ++nj)
        acc[mi][nj] = MFMA16(af[mi], bfr[nj], acc[mi][nj]);
  }
  if (typ == 2) {
    // Symmetry trick: store frag at the TRANSPOSED location -> float4 stores.
    float* O = out + OFF_VAL + (size_t)bh * (1024ull * 1024);
    #pragma unroll
    for (int nj = 0; nj < 4; ++nj)
      #pragma unroll
      for (int mi = 0; mi < 4; ++mi) {
        f32x4 v = acc[mi][nj] * 0.125f;
        *(f32x4*)(O + (size_t)(n0 + wn * 64 + nj * 16 + l15) * 1024 +
                  (m0 + wm * 64 + mi * 16 + g * 4)) = v;
      }
  } else {
    // Same transposed layout, 4B-aligned vector stores (odd output base).
    float* O = out + (typ == 0 ? OFF_QRY : OFF_KEY) + (size_t)bh * (1024ull * 1024);
    #pragma unroll
    for (int nj = 0; nj < 4; ++nj)
      #pragma unroll
      for (int mi = 0; mi < 4; ++mi) {
        f32x4 v = acc[mi][nj] * 0.125f;
        *(f32x4_a4*)(O + (size_t)(n0 + wn * 64 + nj * 16 + l15) * 1024 +
                     (m0 + wm * 64 + mi * 16 + g * 4)) = v;
      }
  }
}

// ---------------------------------------------------------------------------
// Device part B: fused attention_scores write + online softmax + context.
// S^T = mfma(K, Q) so each lane owns one q-row. fid in [0,768).
// DELTA vs R11: P-buffer reuses the K-tile LDS region (K fully consumed by
// QK^T within the iteration; extra barrier before the P write). Kernel LDS
// 49152 -> 32768 => 5 blocks/CU. V staging UNCHANGED (isolates occupancy).
// ---------------------------------------------------------------------------
__device__ __forceinline__ void flash_part(
    char* lds, int fid, const unsigned short* __restrict__ qkv,
    const unsigned short* __restrict__ vt, const float* __restrict__ mask,
    float* __restrict__ out)
{
  const int t = threadIdx.x;
  const int lane = t & 63, w = t >> 6;
  const int g = lane >> 4, l15 = lane & 15;
  const int q0 = (fid & 15) * 64;
  const int bh = fid >> 4, b = bh / NHEAD, h = bh % NHEAD;
  const unsigned short* Qp  = qkv + (size_t)bh * (S_LEN * 64);
  const unsigned short* Kp  = qkv + NQ + (size_t)bh * (S_LEN * 64);
  const unsigned short* Vtp = vt + (size_t)bh * (S_LEN * 64);
  const int qrow = q0 + w * 16 + l15;  // this lane's q row

  bf16x8 qf[2];
  qf[0] = *(const bf16x8*)(Qp + (size_t)qrow * 64 + g * 8);
  qf[1] = *(const bf16x8*)(Qp + (size_t)qrow * 64 + 32 + g * 8);

  float m_run = -1e30f, l_run = 0.f;
  f32x4 o[4] = {};
  float* att = out + OFF_ATT + (size_t)bh * (1024ull * 1024) + (size_t)qrow * 1024;
  const float* mrow = mask + b * S_LEN;
  const int sr2 = t >> 1, hf = t & 1;  // K staging: 128 rows x 128B
  const int sr4 = t >> 2, qr = t & 3;  // Vt staging: 64 rows x 256B
  char* Plds = lds + w * 4096;         // per-wave P slice INSIDE the K region

  for (int kt = 0; kt < 8; ++kt) {
    __syncthreads();  // prev iteration's P/V reads done -> safe to restage
    {
      const uint4* sk = (const uint4*)(Kp + (size_t)(kt * 128 + sr2) * 64 + hf * 32);
      #pragma unroll
      for (int j = 0; j < 4; ++j)
        *(uint4*)(lds + swz(sr2, hf * 64 + j * 16, 128)) = sk[j];
      const uint4* sv = (const uint4*)(Vtp + (size_t)sr4 * S_LEN + kt * 128 + qr * 32);
      #pragma unroll
      for (int j = 0; j < 4; ++j)
        *(uint4*)(lds + 16384 + swz(sr4, qr * 64 + j * 16, 256)) = sv[j];
    }
    __syncthreads();

    // S^T[k][q] = sum_d K[k][d] Q[q][d]
    f32x4 st[8] = {};
    #pragma unroll
    for (int kk = 0; kk < 2; ++kk)
      #pragma unroll
      for (int mi = 0; mi < 8; ++mi) {
        bf16x8 a = *(const bf16x8*)(lds + swz(mi * 16 + l15, kk * 64 + g * 16, 128));
        st[mi] = MFMA16(a, qf[kk], st[mi]);
      }

    // scale + mask + write scores (lane holds 4 consecutive k for its q row)
    float tmax = -1e30f;
    #pragma unroll
    for (int mi = 0; mi < 8; ++mi) {
      f32x4 mk = *(const f32x4*)(mrow + kt * 128 + mi * 16 + g * 4);
      st[mi] = st[mi] * 0.125f + mk;
      *(f32x4*)(att + kt * 128 + mi * 16 + g * 4) = st[mi];
      #pragma unroll
      for (int r = 0; r < 4; ++r) tmax = fmaxf(tmax, st[mi][r]);
    }
    tmax = fmaxf(tmax, __shfl_xor(tmax, 16));
    tmax = fmaxf(tmax, __shfl_xor(tmax, 32));
    const float mnew = fmaxf(m_run, tmax);
    const float corr = __expf(m_run - mnew);
    float tsum = 0.f;
    #pragma unroll
    for (int mi = 0; mi < 8; ++mi)
      #pragma unroll
      for (int r = 0; r < 4; ++r) {
        float p = __expf(st[mi][r] - mnew);
        st[mi][r] = p;
        tsum += p;
      }
    tsum += __shfl_xor(tsum, 16);
    tsum += __shfl_xor(tsum, 32);
    l_run = l_run * corr + tsum;
    m_run = mnew;
    #pragma unroll
    for (int dj = 0; dj < 4; ++dj) o[dj] *= corr;

    __syncthreads();  // NEW: all waves done reading K -> safe to overwrite w/ P

    // P -> bf16 -> per-wave LDS slice [16 q rows][128 k] (in K region)
    #pragma unroll
    for (int mi = 0; mi < 8; ++mi) {
      uint2 pw = make_uint2(pk2(st[mi][0], st[mi][1]), pk2(st[mi][2], st[mi][3]));
      *(uint2*)(Plds + swz(l15, mi * 32 + g * 8, 256)) = pw;
    }
    // O^T[d][q] += sum_k Vt[d][k] P[q][k]  (P is same-wave data: no barrier)
    #pragma unroll
    for (int kk2 = 0; kk2 < 4; ++kk2) {
      bf16x8 pa = *(const bf16x8*)(Plds + swz(l15, kk2 * 64 + g * 16, 256));
      #pragma unroll
      for (int dj = 0; dj < 4; ++dj) {
        bf16x8 va = *(const bf16x8*)(lds + 16384 + swz(dj * 16 + l15, kk2 * 64 + g * 16, 256));
        o[dj] = MFMA16(va, pa, o[dj]);
      }
    }
  }

  const float inv = 1.f / l_run;
  #pragma unroll
  for (int dj = 0; dj < 4; ++dj) {
    f32x4 v = o[dj] * inv;
    *(f32x4*)(out + ((size_t)b * S_LEN + qrow) * 768 + h * 64 + dj * 16 + g * 4) = v;
  }
}

// ---------------------------------------------------------------------------
// Kernel 2: merged sym+flash. Grid 9984 = 768*13, XCD-aware bijective swizzle
// (9984 = 8 x 1248). 32KB LDS -> 5 blocks/CU (the single delta under test).
// ---------------------------------------------------------------------------
__global__ __launch_bounds__(256) void fused_scores_attn_kernel(
    const unsigned short* __restrict__ qkv, const unsigned short* __restrict__ vt,
    const float* __restrict__ mask, float* __restrict__ out)
{
  __shared__ char lds[32768];
  const int bid0 = blockIdx.x;
  const int bid = (bid0 & 7) * 1248 + (bid0 >> 3);  // XCD-chunked logical id
  if (bid == 9983 && threadIdx.x == 0) out[OFF_CSC] = 0.f;
  if (bid % 13 == 0) {
    flash_part(lds, bid / 13, qkv, vt, mask, out);
  } else {
    sym_part(lds, bid - bid / 13 - 1, qkv, out);
  }
}

extern "C" void kernel_launch(void* const* d_in, const int* in_sizes, int n_in,
                              void* d_out, int out_size, void* d_ws, size_t ws_size,
                              hipStream_t stream) {
  (void)in_sizes; (void)n_in; (void)out_size; (void)ws_size;
  const float* X  = (const float*)d_in[0];
  const float* mk = (const float*)d_in[1];
  const float* Wq = (const float*)d_in[2];
  const float* bq = (const float*)d_in[3];
  const float* Wk = (const float*)d_in[4];
  const float* bk = (const float*)d_in[5];
  const float* Wv = (const float*)d_in[6];
  const float* bv = (const float*)d_in[7];
  float* out = (float*)d_out;
  unsigned short* ws = (unsigned short*)d_ws;
  unsigned short* qkv = ws;            // bf16 Q|K|V [B,H,S,D]
  unsigned short* vt  = ws + WS_VT;    // bf16 Vt [B,H,D,S]
  unsigned short* xb  = ws + WS_XB;    // bf16 X, then W concat at WS_WB

  tobf16_kernel<<<2400, 256, 0, stream>>>(X, Wq, Wk, Wv, xb);
  qkv_gemm_kernel<<<dim3(32, 18), 256, 0, stream>>>(xb, ws + WS_WB, bq, bk, bv, qkv, vt);
  fused_scores_attn_kernel<<<9984, 256, 0, stream>>>(qkv, vt, mk, out);
}